// Round 20
// baseline (188.394 us; speedup 1.0000x reference)
//
#include <hip/hip_runtime.h>
#include <math.h>

#define NB 4
#define NC 64
#define NC8 8
#define NCC 21
#define NHW 4096
#define NHM 128

typedef __attribute__((ext_vector_type(8))) short bf16x8;
typedef __attribute__((ext_vector_type(8))) unsigned short ushort8;
typedef __attribute__((ext_vector_type(4))) float f32x4;

__device__ __forceinline__ float gelu_exact(float x) {
    return 0.5f * x * (1.0f + erff(x * 0.70710678118654752f));
}

__device__ __forceinline__ unsigned short f2bf(float x) {
    union { float f; unsigned u; } u; u.f = x;
    unsigned r = u.u + 0x7fffu + ((u.u >> 16) & 1u);   // RNE
    return (unsigned short)(r >> 16);
}

__device__ __forceinline__ float bf2f(unsigned short v) {
    union { unsigned u; float f; } t; t.u = (unsigned)v << 16; return t.f;
}

// ---------------- merged: weight pack (bid<244) + LayerNorm+qkv (bid>=244) ----------------
__global__ __launch_bounds__(256) void k_prep(const float* __restrict__ qw, const float* __restrict__ kw,
                     const float* __restrict__ vw, const float* __restrict__ c1w,
                     const float* __restrict__ c2w, const float* __restrict__ pw,
                     const float* __restrict__ f1w, const float* __restrict__ f2w,
                     float* __restrict__ o, float* __restrict__ pool,
                     const float* __restrict__ x, const float* __restrict__ lnw,
                     const float* __restrict__ lnb,
                     const float* __restrict__ qb, const float* __restrict__ kb,
                     const float* __restrict__ vb,
                     unsigned short* __restrict__ xnT,
                     unsigned short* __restrict__ q1, unsigned short* __restrict__ k1,
                     unsigned short* __restrict__ v1) {
    int bid = blockIdx.x;
    int tid = threadIdx.x;
    if (bid < 244) {
        int idx = bid * 256 + tid;
        if (idx < 256) pool[idx] = 0.f;
        if (idx < 5120) {
            int ci = idx / 80, j = idx - ci * 80;
            float v = j < 8 ? qw[j * 64 + ci] : (j < 16 ? kw[(j - 8) * 64 + ci] : vw[(j - 16) * 64 + ci]);
            o[idx] = v;
        } else if (idx < 9216) {
            int r = idx - 5120; int co = r & 63, ci = r >> 6;
            o[idx] = pw[co * 64 + ci];
        } else if (idx < 27648) {
            int r = idx - 9216;
            int j = r & 7, l = (r >> 3) & 63, s = (r >> 9) % 18, f = r / 9216;
            int co = f * 16 + (l & 15);
            int k = s * 32 + (l >> 4) * 8 + j;
            int tap = k >> 6, ci = k & 63;
            float v = (co < 21) ? c1w[co * 576 + ci * 9 + tap] : 0.f;
            unsigned short hi = f2bf(v);
            unsigned short lo = f2bf(v - bf2f(hi));
            ((unsigned short*)(o + 9216))[r] = hi;
            ((unsigned short*)(o + 18432))[r] = lo;
        } else if (idx < 46080) {
            int r = idx - 27648;
            int j = r & 7, l = (r >> 3) & 63, s = (r >> 9) % 9, f = r / 4608;
            int co = f * 16 + (l & 15);
            int ci = (l >> 4) * 8 + j;
            float v = (ci < 21) ? c2w[co * 189 + ci * 9 + s] : 0.f;
            unsigned short hi = f2bf(v);
            unsigned short lo = f2bf(v - bf2f(hi));
            ((unsigned short*)(o + 27648))[r] = hi;
            ((unsigned short*)(o + 36864))[r] = lo;
        } else if (idx < 54272) {
            int r = idx - 46080;
            int j = r & 7, l = (r >> 3) & 63, q = r >> 9;
            int F = q >> 1, s = q & 1;
            int m = F * 16 + (l & 15);
            int k = s * 32 + (l >> 4) * 8 + j;
            float v = f1w[m * 64 + k];
            unsigned short hi = f2bf(v);
            unsigned short lo = f2bf(v - bf2f(hi));
            ((unsigned short*)(o + 46080))[r] = hi;
            ((unsigned short*)(o + 50176))[r] = lo;
        } else if (idx < 62464) {
            int r = idx - 54272;
            int j = r & 7, l = (r >> 3) & 63, q = r >> 9;
            int F2 = q >> 2, s = q & 3;
            int wo = F2 * 16 + (l & 15);
            int k = s * 32 + (l >> 4) * 8 + j;
            float v = f2w[wo * 128 + k];
            unsigned short hi = f2bf(v);
            unsigned short lo = f2bf(v - bf2f(hi));
            ((unsigned short*)(o + 54272))[r] = hi;
            ((unsigned short*)(o + 58368))[r] = lo;
        }
        return;
    }
    // ---- LayerNorm + qkv part (64 pixels per block) ----
    __shared__ float Xs[64][64];
    __shared__ float Ws[64][80];
    __shared__ float r1[4][64], r2[4][64];
    int lb = bid - 244;
    int pl = tid & 63, cq = tid >> 6;
    int b = lb >> 6;
    int pix0 = (lb & 63) * 64;
    int pix = pix0 + pl;
    for (int i = tid; i < 5120; i += 256) {
        int ci = i / 80, j = i - ci * 80;
        float v = j < 8 ? qw[j * 64 + ci] : (j < 16 ? kw[(j - 8) * 64 + ci] : vw[(j - 16) * 64 + ci]);
        ((float*)Ws)[i] = v;
    }
    const float* p = x + (size_t)b * NC * NHW + pix;
    float v[16]; float s = 0.f, ss = 0.f;
    #pragma unroll
    for (int k = 0; k < 16; ++k) {
        float f = p[(size_t)(cq * 16 + k) * NHW];
        v[k] = f; s += f; ss += f * f;
    }
    r1[cq][pl] = s; r2[cq][pl] = ss;
    __syncthreads();
    float S  = r1[0][pl] + r1[1][pl] + r1[2][pl] + r1[3][pl];
    float SS = r2[0][pl] + r2[1][pl] + r2[2][pl] + r2[3][pl];
    float mean = S * (1.0f / 64);
    float rstd = rsqrtf(SS * (1.0f / 64) - mean * mean + 1e-5f);
    ushort8 t0, t1;
    #pragma unroll
    for (int k = 0; k < 16; ++k) {
        int c = cq * 16 + k;
        float nv = (v[k] - mean) * rstd * lnw[c] + lnb[c];
        Xs[c][pl] = nv;
        unsigned short bv = f2bf(nv);
        if (k < 8) t0[k] = bv; else t1[k - 8] = bv;
    }
    unsigned short* tp = xnT + ((size_t)b * NHW + pix) * 64 + cq * 16;
    *(ushort8*)tp = t0;
    *(ushort8*)(tp + 8) = t1;
    __syncthreads();
    int co0 = cq * 20;
    float acc[20];
    #pragma unroll
    for (int j = 0; j < 20; ++j) acc[j] = 0.f;
    for (int ci = 0; ci < 64; ++ci) {
        float xv = Xs[ci][pl];
        const float* wr = &Ws[ci][co0];
        #pragma unroll
        for (int j = 0; j < 20; ++j) acc[j] = fmaf(xv, wr[j], acc[j]);
    }
    #pragma unroll
    for (int j = 0; j < 20; ++j) {
        int co = co0 + j;
        float bsv; unsigned short* dst;
        if (co < 8)       { bsv = qb[co];      dst = q1 + ((size_t)b * NC8 + co) * NHW + pix; }
        else if (co < 16) { bsv = kb[co - 8];  dst = k1 + ((size_t)b * NC8 + co - 8) * NHW + pix; }
        else              { bsv = vb[co - 16]; dst = v1 + ((size_t)b * NC + co - 16) * NHW + pix; }
        *dst = f2bf(acc[j] + bsv);
    }
}

// ---------------- merged: VECTORIZED depthwise 3x3 (bid<320) + CAB conv1 MFMA (bid>=320) ----
__global__ __launch_bounds__(512) void k_dwcab1(
        const unsigned short* __restrict__ q1, const unsigned short* __restrict__ k1,
        const unsigned short* __restrict__ v1,
        const float* __restrict__ qkw, const float* __restrict__ qkb,
        const float* __restrict__ vw, const float* __restrict__ vb,
        unsigned short* __restrict__ qdb, unsigned short* __restrict__ kdb,
        unsigned short* __restrict__ v8,
        const unsigned short* __restrict__ xnT,
        const unsigned short* __restrict__ Ah, const unsigned short* __restrict__ Al,
        const float* __restrict__ bias, unsigned short* __restrict__ y1T) {
    __shared__ float Rs[2048];
    int bid = blockIdx.x;
    int tid = threadIdx.x;
    if (bid < 320) {
        int yv = bid % 80, b = bid / 80;
        int y = tid >> 3, x0 = (tid & 7) * 8;
        const unsigned short* ip;
        const float* wp;
        float bs;
        if (yv < 16) {
            int c = yv & 7;
            ip = (yv < 8 ? q1 : k1) + ((size_t)b * NC8 + c) * NHW;
            wp = qkw + c * 9; bs = qkb[c];
        } else {
            int c = yv - 16;
            ip = v1 + ((size_t)b * NC + c) * NHW;
            wp = vw + c * 9; bs = vb[c];
        }
        float w9[9];
        #pragma unroll
        for (int t = 0; t < 9; ++t) w9[t] = wp[t];
        float acc[8];
        #pragma unroll
        for (int j = 0; j < 8; ++j) acc[j] = bs;
        #pragma unroll
        for (int dy = -1; dy <= 1; ++dy) {
            int yy = y + dy;
            if ((unsigned)yy >= 64u) continue;
            const unsigned short* rp = ip + yy * 64;
            float cv[10];
            cv[0] = (x0 > 0) ? bf2f(rp[x0 - 1]) : 0.f;
            ushort8 ctr = *(const ushort8*)(rp + x0);
            #pragma unroll
            for (int j = 0; j < 8; ++j) cv[j + 1] = bf2f(ctr[j]);
            cv[9] = (x0 + 8 < 64) ? bf2f(rp[x0 + 8]) : 0.f;
            const float* wr = &w9[(dy + 1) * 3];
            #pragma unroll
            for (int j = 0; j < 8; ++j)
                acc[j] = fmaf(wr[0], cv[j], fmaf(wr[1], cv[j + 1], fmaf(wr[2], cv[j + 2], acc[j])));
        }
        int px0 = tid * 8;
        if (yv < 16) {
            int c = yv & 7;
            unsigned short* outp = (yv < 8 ? qdb : kdb) + ((size_t)b * NHW + px0) * NC8 + c;
            #pragma unroll
            for (int j = 0; j < 8; ++j) outp[j * NC8] = f2bf(acc[j]);
        } else {
            int c = yv - 16;
            ushort8 pk;
            #pragma unroll
            for (int j = 0; j < 8; ++j) pk[j] = f2bf(acc[j]);
            *(ushort8*)(v8 + (((size_t)b * 512 + (px0 >> 3)) * NC + c) * 8) = pk;
        }
        return;
    }
    int r = bid - 320;
    int y = r & 63, b = r >> 6;
    int w = tid >> 6, lane = tid & 63;
    int il = lane & 15, g = lane >> 4;
    int frag = w & 3, kh = w >> 2;
    int xloc = frag * 16 + il;
    f32x4 acc[2];
    acc[0] = (f32x4){0.f, 0.f, 0.f, 0.f};
    acc[1] = (f32x4){0.f, 0.f, 0.f, 0.f};
    #pragma unroll
    for (int si = 0; si < 9; ++si) {
        int s = kh * 9 + si;
        int tap = s >> 1;
        int ci0 = (s & 1) * 32;
        int dyv = tap / 3 - 1, dxv = tap - (tap / 3) * 3 - 1;
        int xx = xloc + dxv, yy = y + dyv;
        bf16x8 bv = (bf16x8)(short)0;
        if (((unsigned)xx < 64u) && ((unsigned)yy < 64u))
            bv = *(const bf16x8*)(xnT + ((size_t)b * NHW + yy * 64 + xx) * 64 + ci0 + g * 8);
        #pragma unroll
        for (int f = 0; f < 2; ++f) {
            bf16x8 ahv = *(const bf16x8*)(Ah + ((size_t)(f * 18 + s) * 64 + lane) * 8);
            bf16x8 alv = *(const bf16x8*)(Al + ((size_t)(f * 18 + s) * 64 + lane) * 8);
            acc[f] = __builtin_amdgcn_mfma_f32_16x16x32_bf16(ahv, bv, acc[f], 0, 0, 0);
            acc[f] = __builtin_amdgcn_mfma_f32_16x16x32_bf16(alv, bv, acc[f], 0, 0, 0);
        }
    }
    if (kh == 1) {
        #pragma unroll
        for (int f = 0; f < 2; ++f)
            #pragma unroll
            for (int e = 0; e < 4; ++e)
                Rs[((frag * 2 + f) * 4 + e) * 64 + lane] = acc[f][e];
    }
    __syncthreads();
    if (kh == 0) {
        #pragma unroll
        for (int f = 0; f < 2; ++f) {
            ushort4 pk;
            #pragma unroll
            for (int e = 0; e < 4; ++e) {
                float v = acc[f][e] + Rs[((frag * 2 + f) * 4 + e) * 64 + lane];
                int co = f * 16 + g * 4 + e;
                float rr = 0.f;
                if (co < 21) rr = gelu_exact(v + bias[co]);
                ((unsigned short*)&pk)[e] = f2bf(rr);
            }
            *(ushort4*)(y1T + ((size_t)b * NHW + y * 64 + xloc) * 32 + f * 16 + g * 4) = pk;
        }
    }
}

// ---------------- merged: flash attention (bid<512) + CAB conv2 MFMA (bid>=512) ----------------
__global__ __launch_bounds__(512) void k_flashcab2(
        const unsigned short* __restrict__ qdb, const unsigned short* __restrict__ kdb,
        const unsigned short* __restrict__ v8, unsigned short* __restrict__ O,
        const unsigned short* __restrict__ y1T,
        const unsigned short* __restrict__ Ah, const unsigned short* __restrict__ Al,
        const float* __restrict__ bias, unsigned short* __restrict__ ycT,
        float* __restrict__ pool) {
    __shared__ __align__(16) char smem[35840];
    int bid = blockIdx.x;
    int tid = threadIdx.x;
    int w = tid >> 6, lane = tid & 63;
    int g = lane >> 4, il = lane & 15;
    if (bid < 512) {
        int i0 = (bid & 127) * 32, b = bid >> 7;
        unsigned short (*P)[72] = (unsigned short (*)[72])(smem + w * 2304);
        bf16x8 qb0 = (bf16x8)(short)0, qb1 = (bf16x8)(short)0;
        if (g == 0) {
            qb0 = *(const bf16x8*)(qdb + (size_t)(b * NHW + i0 + il) * NC8);
            qb1 = *(const bf16x8*)(qdb + (size_t)(b * NHW + i0 + 16 + il) * NC8);
        }
        f32x4 acc0[4], acc1[4];
        #pragma unroll
        for (int ct = 0; ct < 4; ++ct) {
            acc0[ct] = (f32x4){0.f, 0.f, 0.f, 0.f};
            acc1[ct] = (f32x4){0.f, 0.f, 0.f, 0.f};
        }
        float La0 = 0.f, La1 = 0.f;
        bf16x8 kn[4];
        #pragma unroll
        for (int t = 0; t < 4; ++t) {
            kn[t] = (bf16x8)(short)0;
            if (g == 0) kn[t] = *(const bf16x8*)(kdb + (size_t)(b * NHW + w * 512 + 16 * t + il) * NC8);
        }
        for (int jt = 0; jt < 8; ++jt) {
            int j0 = w * 512 + jt * 64;
            int ch0 = b * 512 + (j0 >> 3);
            bf16x8 va[2][4];
            #pragma unroll
            for (int kc = 0; kc < 2; ++kc)
                #pragma unroll
                for (int ct = 0; ct < 4; ++ct)
                    va[kc][ct] = *(const bf16x8*)(v8 +
                        ((size_t)(ch0 + kc * 4 + g) * NC + ct * 16 + il) * 8);
            bf16x8 ka[4];
            #pragma unroll
            for (int t = 0; t < 4; ++t) ka[t] = kn[t];
            if (jt < 7) {
                #pragma unroll
                for (int t = 0; t < 4; ++t) {
                    kn[t] = (bf16x8)(short)0;
                    if (g == 0) kn[t] = *(const bf16x8*)(kdb + (size_t)(b * NHW + j0 + 64 + 16 * t + il) * NC8);
                }
            }
            #pragma unroll
            for (int t = 0; t < 4; ++t) {
                f32x4 sv = __builtin_amdgcn_mfma_f32_16x16x32_bf16(ka[t], qb0, (f32x4){0.f, 0.f, 0.f, 0.f}, 0, 0, 0);
                float p0 = __expf(sv[0]), p1 = __expf(sv[1]);
                float p2 = __expf(sv[2]), p3 = __expf(sv[3]);
                La0 += (p0 + p1) + (p2 + p3);
                ushort4 pk;
                pk.x = f2bf(p0); pk.y = f2bf(p1); pk.z = f2bf(p2); pk.w = f2bf(p3);
                *(ushort4*)&P[il][16 * t + 4 * g] = pk;
            }
            #pragma unroll
            for (int kc = 0; kc < 2; ++kc) {
                bf16x8 pb = *(const bf16x8*)&P[il][kc * 32 + 8 * g];
                #pragma unroll
                for (int ct = 0; ct < 4; ++ct)
                    acc0[ct] = __builtin_amdgcn_mfma_f32_16x16x32_bf16(va[kc][ct], pb, acc0[ct], 0, 0, 0);
            }
            #pragma unroll
            for (int t = 0; t < 4; ++t) {
                f32x4 sv = __builtin_amdgcn_mfma_f32_16x16x32_bf16(ka[t], qb1, (f32x4){0.f, 0.f, 0.f, 0.f}, 0, 0, 0);
                float p0 = __expf(sv[0]), p1 = __expf(sv[1]);
                float p2 = __expf(sv[2]), p3 = __expf(sv[3]);
                La1 += (p0 + p1) + (p2 + p3);
                ushort4 pk;
                pk.x = f2bf(p0); pk.y = f2bf(p1); pk.z = f2bf(p2); pk.w = f2bf(p3);
                *(ushort4*)&P[il][16 * t + 4 * g] = pk;
            }
            #pragma unroll
            for (int kc = 0; kc < 2; ++kc) {
                bf16x8 pb = *(const bf16x8*)&P[il][kc * 32 + 8 * g];
                #pragma unroll
                for (int ct = 0; ct < 4; ++ct)
                    acc1[ct] = __builtin_amdgcn_mfma_f32_16x16x32_bf16(va[kc][ct], pb, acc1[ct], 0, 0, 0);
            }
        }
        La0 += __shfl_xor(La0, 16, 64); La0 += __shfl_xor(La0, 32, 64);
        La1 += __shfl_xor(La1, 16, 64); La1 += __shfl_xor(La1, 32, 64);

        __syncthreads();
        unsigned short* Ocm = (unsigned short*)smem;
        float* Lw = (float*)(smem + 34816);
        #pragma unroll
        for (int ct = 0; ct < 4; ++ct)
            #pragma unroll
            for (int e = 0; e < 4; ++e) {
                int c = ct * 16 + 4 * g + e;
                Ocm[(w * 2 + 0) * 1088 + c * 17 + il] = f2bf(acc0[ct][e]);
                Ocm[(w * 2 + 1) * 1088 + c * 17 + il] = f2bf(acc1[ct][e]);
            }
        if (lane < 16) {
            Lw[(w * 2 + 0) * 16 + il] = La0;
            Lw[(w * 2 + 1) * 16 + il] = La1;
        }
        __syncthreads();

        int st = tid >> 8, rem = tid & 255;
        int ic = rem & 15, ch = rem >> 4;
        float l = 0.f;
        #pragma unroll
        for (int w2 = 0; w2 < 8; ++w2) l += Lw[(w2 * 2 + st) * 16 + ic];
        float rl = 1.0f / l;
        #pragma unroll
        for (int cc = 0; cc < 4; ++cc) {
            int c = cc * 16 + ch;
            float o = 0.f;
            #pragma unroll
            for (int w2 = 0; w2 < 8; ++w2) o += bf2f(Ocm[(w2 * 2 + st) * 1088 + c * 17 + ic]);
            O[(size_t)(b * NC + c) * NHW + i0 + st * 16 + ic] = f2bf(o * rl);
        }
        return;
    }
    float* Rs = (float*)smem;
    float (*Ssum)[64] = (float (*)[64])(smem + 16384);
    int r = bid - 512;
    int y = r & 63, b = r >> 6;
    int frag = w & 3, kh = w >> 2;
    int xloc = frag * 16 + il;
    f32x4 acc[4];
    #pragma unroll
    for (int f = 0; f < 4; ++f) acc[f] = (f32x4){0.f, 0.f, 0.f, 0.f};
    #pragma unroll
    for (int si = 0; si < 5; ++si) {
        if (!(kh == 1 && si == 4)) {
            int s = kh * 5 + si;
            int dyv = s / 3 - 1, dxv = s - (s / 3) * 3 - 1;
            int xx = xloc + dxv, yy = y + dyv;
            bf16x8 bv = (bf16x8)(short)0;
            if (((unsigned)xx < 64u) && ((unsigned)yy < 64u))
                bv = *(const bf16x8*)(y1T + ((size_t)b * NHW + yy * 64 + xx) * 32 + g * 8);
            #pragma unroll
            for (int f = 0; f < 4; ++f) {
                bf16x8 ahv = *(const bf16x8*)(Ah + ((size_t)(f * 9 + s) * 64 + lane) * 8);
                bf16x8 alv = *(const bf16x8*)(Al + ((size_t)(f * 9 + s) * 64 + lane) * 8);
                acc[f] = __builtin_amdgcn_mfma_f32_16x16x32_bf16(ahv, bv, acc[f], 0, 0, 0);
                acc[f] = __builtin_amdgcn_mfma_f32_16x16x32_bf16(alv, bv, acc[f], 0, 0, 0);
            }
        }
    }
    if (kh == 1) {
        #pragma unroll
        for (int f = 0; f < 4; ++f)
            #pragma unroll
            for (int e = 0; e < 4; ++e)
                Rs[((frag * 4 + f) * 4 + e) * 64 + lane] = acc[f][e];
    }
    __syncthreads();
    if (kh == 0) {
        #pragma unroll
        for (int f = 0; f < 4; ++f) {
            ushort4 pk;
            #pragma unroll
            for (int e = 0; e < 4; ++e) {
                int co = f * 16 + g * 4 + e;
                float v = acc[f][e] + Rs[((frag * 4 + f) * 4 + e) * 64 + lane] + bias[co];
                ((unsigned short*)&pk)[e] = f2bf(v);
                float ps = v;
                ps += __shfl_xor(ps, 1, 64);
                ps += __shfl_xor(ps, 2, 64);
                ps += __shfl_xor(ps, 4, 64);
                ps += __shfl_xor(ps, 8, 64);
                if (il == 0) Ssum[frag][co] = ps;
            }
            *(ushort4*)(ycT + ((size_t)b * NHW + y * 64 + xloc) * 64 + f * 16 + g * 4) = pk;
        }
    }
    __syncthreads();
    if (tid < 64) {
        float t = Ssum[0][tid] + Ssum[1][tid] + Ssum[2][tid] + Ssum[3][tid];
        atomicAdd(&pool[b * NC + tid], t);
    }
}

// ---------------- proj + CA + residuals + fused LN2; fs1T channel-last out ----------------
__global__ __launch_bounds__(512) void k_fsum2(const unsigned short* __restrict__ O,
        const float* __restrict__ pwt, const float* __restrict__ pb,
        const float* __restrict__ gamma, const unsigned short* __restrict__ xnT,
        const unsigned short* __restrict__ ycT, const float* __restrict__ pool,
        const float* __restrict__ cw1, const float* __restrict__ cb1,
        const float* __restrict__ cw2, const float* __restrict__ cb2,
        const float* __restrict__ x, const float* __restrict__ lnw,
        const float* __restrict__ lnb, unsigned short* __restrict__ fsum,
        unsigned short* __restrict__ fs1T) {
    __shared__ unsigned short Os[64][64];
    __shared__ float Ws[64][64];
    __shared__ float Fs[64][66];
    __shared__ float mean_s[64], rstd_s[64];
    int tid = threadIdx.x;
    int pix0 = blockIdx.x * 64, b = blockIdx.y;
    for (int i = tid; i < 1024; i += 512) {
        int c = i >> 4, q4 = i & 15;
        *(ushort4*)&Os[c][q4 * 4] = *(const ushort4*)(O + ((size_t)b * NC + c) * NHW + pix0 + q4 * 4);
    }
    for (int i = tid; i < 1024; i += 512)
        *(float4*)&((float*)Ws)[i * 4] = *(const float4*)&pwt[i * 4];
    __syncthreads();
    float h0 = cb1[0], h1 = cb1[1];
    for (int ci = 0; ci < NC; ++ci) {
        float pv = pool[b * NC + ci] * (1.0f / NHW);
        h0 += cw1[ci] * pv;
        h1 += cw1[NC + ci] * pv;
    }
    h0 = fmaxf(h0, 0.f); h1 = fmaxf(h1, 0.f);
    int p2 = (tid & 31) * 2, g = tid >> 5;
    int co0 = g * 4;
    float scv[4];
    #pragma unroll
    for (int j = 0; j < 4; ++j) {
        int c = co0 + j;
        float z = cw2[c * 2] * h0 + cw2[c * 2 + 1] * h1 + cb2[c];
        scv[j] = 1.0f / (1.0f + __expf(-z));
    }
    float a0[4], a1[4];
    #pragma unroll
    for (int j = 0; j < 4; ++j) { a0[j] = 0.f; a1[j] = 0.f; }
    for (int ci = 0; ci < 64; ++ci) {
        ushort2 uv = *(const ushort2*)&Os[ci][p2];
        float ox = bf2f(uv.x), oy = bf2f(uv.y);
        float wv[4];
        *(float4*)wv = *(const float4*)&Ws[ci][co0];
        #pragma unroll
        for (int j = 0; j < 4; ++j) {
            a0[j] = fmaf(ox, wv[j], a0[j]);
            a1[j] = fmaf(oy, wv[j], a1[j]);
        }
    }
    float gg = gamma[0];
    size_t base = (size_t)b * NC * NHW + pix0 + p2;
    const unsigned short* xtp = xnT + ((size_t)b * NHW + pix0 + p2) * 64 + co0;
    const unsigned short* ytp = ycT + ((size_t)b * NHW + pix0 + p2) * 64 + co0;
    ushort4 xa = *(const ushort4*)xtp, xb = *(const ushort4*)(xtp + 64);
    ushort4 ya = *(const ushort4*)ytp, yb = *(const ushort4*)(ytp + 64);
    float f0[4], f1[4];
    #pragma unroll
    for (int j = 0; j < 4; ++j) {
        int c = co0 + j;
        size_t n = base + (size_t)c * NHW;
        float pbv = pb[c];
        float2 xv = *(const float2*)&x[n];
        f0[j] = gg * (a0[j] + pbv) + bf2f(((const unsigned short*)&xa)[j])
              + bf2f(((const unsigned short*)&ya)[j]) * scv[j] + xv.x;
        f1[j] = gg * (a1[j] + pbv) + bf2f(((const unsigned short*)&xb)[j])
              + bf2f(((const unsigned short*)&yb)[j]) * scv[j] + xv.y;
        ushort2 o = { f2bf(f0[j]), f2bf(f1[j]) };
        *(ushort2*)&fsum[n] = o;
        Fs[c][p2] = f0[j]; Fs[c][p2 + 1] = f1[j];
    }
    __syncthreads();
    if (tid < 64) {
        float s = 0.f, ss = 0.f;
        for (int c = 0; c < 64; ++c) { float v = Fs[c][tid]; s += v; ss += v * v; }
        float mean = s * (1.0f / 64);
        mean_s[tid] = mean;
        rstd_s[tid] = rsqrtf(ss * (1.0f / 64) - mean * mean + 1e-5f);
    }
    __syncthreads();
    float m0 = mean_s[p2], r0 = rstd_s[p2];
    float m1 = mean_s[p2 + 1], r1 = rstd_s[p2 + 1];
    ushort4 oA, oB;
    #pragma unroll
    for (int j = 0; j < 4; ++j) {
        int c = co0 + j;
        float lw = lnw[c], lb = lnb[c];
        ((unsigned short*)&oA)[j] = f2bf((f0[j] - m0) * r0 * lw + lb);
        ((unsigned short*)&oB)[j] = f2bf((f1[j] - m1) * r1 * lw + lb);
    }
    unsigned short* fp = fs1T + ((size_t)b * NHW + pix0 + p2) * 64 + co0;
    *(ushort4*)fp = oA;
    *(ushort4*)(fp + 64) = oB;
}

// ---------------- fused MLP as MFMA implicit GEMM (cab recipe) ----------------
__global__ __launch_bounds__(512) void k_mlp(const unsigned short* __restrict__ fs1T,
        const unsigned short* __restrict__ A1h, const unsigned short* __restrict__ A1l,
        const float* __restrict__ b1,
        const unsigned short* __restrict__ A2h, const unsigned short* __restrict__ A2l,
        const float* __restrict__ b2,
        const unsigned short* __restrict__ fs, float* __restrict__ out) {
    __shared__ unsigned short Hs[64][136];
    int tid = threadIdx.x;
    int w = tid >> 6, lane = tid & 63;
    int il = lane & 15, g = lane >> 4;
    int frag = w & 3, fh = w >> 2;
    int y = blockIdx.x, b = blockIdx.y;
    int xloc = frag * 16 + il;
    const unsigned short* bp = fs1T + ((size_t)b * NHW + y * 64 + xloc) * 64;
    // ---- fc1 ----
    f32x4 acc[4];
    #pragma unroll
    for (int fi = 0; fi < 4; ++fi) acc[fi] = (f32x4){0.f, 0.f, 0.f, 0.f};
    #pragma unroll
    for (int s = 0; s < 2; ++s) {
        bf16x8 bv = *(const bf16x8*)(bp + s * 32 + g * 8);
        #pragma unroll
        for (int fi = 0; fi < 4; ++fi) {
            int F = fh * 4 + fi;
            bf16x8 ah = *(const bf16x8*)(A1h + ((size_t)(F * 2 + s) * 64 + lane) * 8);
            bf16x8 al = *(const bf16x8*)(A1l + ((size_t)(F * 2 + s) * 64 + lane) * 8);
            acc[fi] = __builtin_amdgcn_mfma_f32_16x16x32_bf16(ah, bv, acc[fi], 0, 0, 0);
            acc[fi] = __builtin_amdgcn_mfma_f32_16x16x32_bf16(al, bv, acc[fi], 0, 0, 0);
        }
    }
    #pragma unroll
    for (int fi = 0; fi < 4; ++fi) {
        int F = fh * 4 + fi;
        ushort4 pk;
        #pragma unroll
        for (int e = 0; e < 4; ++e) {
            int m = F * 16 + g * 4 + e;
            ((unsigned short*)&pk)[e] = f2bf(gelu_exact(acc[fi][e] + b1[m]));
        }
        *(ushort4*)&Hs[xloc][F * 16 + g * 4] = pk;
    }
    __syncthreads();
    // ---- fc2 ----
    f32x4 acc2[2];
    acc2[0] = (f32x4){0.f, 0.f, 0.f, 0.f};
    acc2[1] = (f32x4){0.f, 0.f, 0.f, 0.f};
    #pragma unroll
    for (int s = 0; s < 4; ++s) {
        bf16x8 bv = *(const bf16x8*)&Hs[xloc][s * 32 + g * 8];
        #pragma unroll
        for (int fi = 0; fi < 2; ++fi) {
            int F2 = fh * 2 + fi;
            bf16x8 ah = *(const bf16x8*)(A2h + ((size_t)(F2 * 4 + s) * 64 + lane) * 8);
            bf16x8 al = *(const bf16x8*)(A2l + ((size_t)(F2 * 4 + s) * 64 + lane) * 8);
            acc2[fi] = __builtin_amdgcn_mfma_f32_16x16x32_bf16(ah, bv, acc2[fi], 0, 0, 0);
            acc2[fi] = __builtin_amdgcn_mfma_f32_16x16x32_bf16(al, bv, acc2[fi], 0, 0, 0);
        }
    }
    #pragma unroll
    for (int fi = 0; fi < 2; ++fi) {
        int F2 = fh * 2 + fi;
        int c0 = F2 * 16 + g * 4;
        size_t ob = ((size_t)b * NHW + y * 64 + xloc) * 64 + c0;
        ushort4 rv = *(const ushort4*)&fs[ob];
        float4 o4;
        o4.x = acc2[fi][0] + b2[c0 + 0] + bf2f(rv.x);
        o4.y = acc2[fi][1] + b2[c0 + 1] + bf2f(rv.y);
        o4.z = acc2[fi][2] + b2[c0 + 2] + bf2f(rv.z);
        o4.w = acc2[fi][3] + b2[c0 + 3] + bf2f(rv.w);
        *(float4*)&out[ob] = o4;
    }
}

extern "C" void kernel_launch(void* const* d_in, const int* in_sizes, int n_in,
                              void* d_out, int out_size, void* d_ws, size_t ws_size,
                              hipStream_t stream) {
    const float* x        = (const float*)d_in[0];
    const float* ln_w     = (const float*)d_in[1];
    const float* ln_b     = (const float*)d_in[2];
    const float* q_w      = (const float*)d_in[3];
    const float* q_b      = (const float*)d_in[4];
    const float* k_w      = (const float*)d_in[5];
    const float* k_b      = (const float*)d_in[6];
    const float* v_w      = (const float*)d_in[7];
    const float* v_b      = (const float*)d_in[8];
    const float* qkdw_w   = (const float*)d_in[9];
    const float* qkdw_b   = (const float*)d_in[10];
    const float* vdw_w    = (const float*)d_in[11];
    const float* vdw_b    = (const float*)d_in[12];
    const float* proj_w   = (const float*)d_in[13];
    const float* proj_b   = (const float*)d_in[14];
    const float* gamma    = (const float*)d_in[15];
    const float* cab_w1   = (const float*)d_in[16];
    const float* cab_b1   = (const float*)d_in[17];
    const float* cab_w2   = (const float*)d_in[18];
    const float* cab_b2   = (const float*)d_in[19];
    const float* ca_w1    = (const float*)d_in[20];
    const float* ca_b1    = (const float*)d_in[21];
    const float* ca_w2    = (const float*)d_in[22];
    const float* ca_b2    = (const float*)d_in[23];
    const float* fc1_w    = (const float*)d_in[24];
    const float* fc1_b    = (const float*)d_in[25];
    const float* fc2_w    = (const float*)d_in[26];
    const float* fc2_b    = (const float*)d_in[27];
    float* out = (float*)d_out;

    char* ws = (char*)d_ws;
    size_t off = 0;
    auto alloc = [&](size_t bytes) { void* p = ws + off; off += (bytes + 255) & ~(size_t)255; return p; };
    unsigned short* xnT = (unsigned short*)alloc((size_t)NB * NHW * NC * 2);
    unsigned short* q1  = (unsigned short*)alloc((size_t)NB * NC8 * NHW * 2);
    unsigned short* k1  = (unsigned short*)alloc((size_t)NB * NC8 * NHW * 2);
    unsigned short* v1  = (unsigned short*)alloc((size_t)NB * NC * NHW * 2);
    unsigned short* qdb = (unsigned short*)alloc((size_t)NB * NHW * NC8 * 2);
    unsigned short* kdb = (unsigned short*)alloc((size_t)NB * NHW * NC8 * 2);
    unsigned short* vdb = (unsigned short*)alloc((size_t)NB * NC * NHW * 2);
    unsigned short* O   = (unsigned short*)alloc((size_t)NB * NC * NHW * 2);
    unsigned short* y1T = (unsigned short*)alloc((size_t)NB * NHW * 32 * 2);
    unsigned short* ycT = (unsigned short*)alloc((size_t)NB * NHW * NC * 2);
    float* pool  = (float*)alloc(256 * 4);
    unsigned short* fsum = (unsigned short*)alloc((size_t)NB * NC * NHW * 2);
    unsigned short* fs1T = (unsigned short*)alloc((size_t)NB * NHW * NC * 2);
    float* wpack = (float*)alloc(62464 * 4);

    float* proj_wt = wpack + 5120;
    unsigned short* cab1Ah = (unsigned short*)(wpack + 9216);
    unsigned short* cab1Al = (unsigned short*)(wpack + 18432);
    unsigned short* cab2Ah = (unsigned short*)(wpack + 27648);
    unsigned short* cab2Al = (unsigned short*)(wpack + 36864);
    unsigned short* fc1h   = (unsigned short*)(wpack + 46080);
    unsigned short* fc1l   = (unsigned short*)(wpack + 50176);
    unsigned short* fc2h   = (unsigned short*)(wpack + 54272);
    unsigned short* fc2l   = (unsigned short*)(wpack + 58368);

    dim3 blk(256);
    dim3 blk5(512);

    k_prep<<<dim3(500), blk, 0, stream>>>(q_w, k_w, v_w, cab_w1, cab_w2, proj_w, fc1_w, fc2_w,
                                          wpack, pool, x, ln_w, ln_b, q_b, k_b, v_b,
                                          xnT, q1, k1, v1);
    k_dwcab1<<<dim3(576), blk5, 0, stream>>>(q1, k1, v1, qkdw_w, qkdw_b, vdw_w, vdw_b,
                                             qdb, kdb, vdb, xnT, cab1Ah, cab1Al, cab_b1, y1T);
    k_flashcab2<<<dim3(768), blk5, 0, stream>>>(qdb, kdb, vdb, O, y1T, cab2Ah, cab2Al,
                                                cab_b2, ycT, pool);
    k_fsum2<<<dim3(64, NB), blk5, 0, stream>>>(O, proj_wt, proj_b, gamma, xnT, ycT, pool,
                                               ca_w1, ca_b1, ca_w2, ca_b2, x, ln_w, ln_b,
                                               fsum, fs1T);
    k_mlp<<<dim3(64, NB), blk5, 0, stream>>>(fs1T, fc1h, fc1l, fc1_b, fc2h, fc2l, fc2_b,
                                             fsum, out);
}

// Round 22
// 182.384 us; speedup vs baseline: 1.0330x; 1.0330x over previous
//
#include <hip/hip_runtime.h>
#include <math.h>

#define NB 4
#define NC 64
#define NC8 8
#define NCC 21
#define NHW 4096
#define NHM 128

typedef __attribute__((ext_vector_type(8))) short bf16x8;
typedef __attribute__((ext_vector_type(8))) unsigned short ushort8;
typedef __attribute__((ext_vector_type(4))) float f32x4;

__device__ __forceinline__ float gelu_exact(float x) {
    return 0.5f * x * (1.0f + erff(x * 0.70710678118654752f));
}

__device__ __forceinline__ unsigned short f2bf(float x) {
    union { float f; unsigned u; } u; u.f = x;
    unsigned r = u.u + 0x7fffu + ((u.u >> 16) & 1u);   // RNE
    return (unsigned short)(r >> 16);
}

__device__ __forceinline__ float bf2f(unsigned short v) {
    union { unsigned u; float f; } t; t.u = (unsigned)v << 16; return t.f;
}

// ---------------- merged: weight pack (bid<244) + LayerNorm+qkv (bid>=244) ----------------
__global__ __launch_bounds__(256) void k_prep(const float* __restrict__ qw, const float* __restrict__ kw,
                     const float* __restrict__ vw, const float* __restrict__ c1w,
                     const float* __restrict__ c2w, const float* __restrict__ pw,
                     const float* __restrict__ f1w, const float* __restrict__ f2w,
                     float* __restrict__ o, float* __restrict__ pool,
                     const float* __restrict__ x, const float* __restrict__ lnw,
                     const float* __restrict__ lnb,
                     const float* __restrict__ qb, const float* __restrict__ kb,
                     const float* __restrict__ vb,
                     unsigned short* __restrict__ xnT,
                     unsigned short* __restrict__ q1, unsigned short* __restrict__ k1,
                     unsigned short* __restrict__ v1) {
    int bid = blockIdx.x;
    int tid = threadIdx.x;
    if (bid < 244) {
        int idx = bid * 256 + tid;
        if (idx < 256) pool[idx] = 0.f;
        if (idx < 5120) {
            int ci = idx / 80, j = idx - ci * 80;
            float v = j < 8 ? qw[j * 64 + ci] : (j < 16 ? kw[(j - 8) * 64 + ci] : vw[(j - 16) * 64 + ci]);
            o[idx] = v;
        } else if (idx < 9216) {
            int r = idx - 5120; int co = r & 63, ci = r >> 6;
            o[idx] = pw[co * 64 + ci];
        } else if (idx < 27648) {
            int r = idx - 9216;
            int j = r & 7, l = (r >> 3) & 63, s = (r >> 9) % 18, f = r / 9216;
            int co = f * 16 + (l & 15);
            int k = s * 32 + (l >> 4) * 8 + j;
            int tap = k >> 6, ci = k & 63;
            float v = (co < 21) ? c1w[co * 576 + ci * 9 + tap] : 0.f;
            unsigned short hi = f2bf(v);
            unsigned short lo = f2bf(v - bf2f(hi));
            ((unsigned short*)(o + 9216))[r] = hi;
            ((unsigned short*)(o + 18432))[r] = lo;
        } else if (idx < 46080) {
            int r = idx - 27648;
            int j = r & 7, l = (r >> 3) & 63, s = (r >> 9) % 9, f = r / 4608;
            int co = f * 16 + (l & 15);
            int ci = (l >> 4) * 8 + j;
            float v = (ci < 21) ? c2w[co * 189 + ci * 9 + s] : 0.f;
            unsigned short hi = f2bf(v);
            unsigned short lo = f2bf(v - bf2f(hi));
            ((unsigned short*)(o + 27648))[r] = hi;
            ((unsigned short*)(o + 36864))[r] = lo;
        } else if (idx < 54272) {
            int r = idx - 46080;
            int j = r & 7, l = (r >> 3) & 63, q = r >> 9;
            int F = q >> 1, s = q & 1;
            int m = F * 16 + (l & 15);
            int k = s * 32 + (l >> 4) * 8 + j;
            float v = f1w[m * 64 + k];
            unsigned short hi = f2bf(v);
            unsigned short lo = f2bf(v - bf2f(hi));
            ((unsigned short*)(o + 46080))[r] = hi;
            ((unsigned short*)(o + 50176))[r] = lo;
        } else if (idx < 62464) {
            int r = idx - 54272;
            int j = r & 7, l = (r >> 3) & 63, q = r >> 9;
            int F2 = q >> 2, s = q & 3;
            int wo = F2 * 16 + (l & 15);
            int k = s * 32 + (l >> 4) * 8 + j;
            float v = f2w[wo * 128 + k];
            unsigned short hi = f2bf(v);
            unsigned short lo = f2bf(v - bf2f(hi));
            ((unsigned short*)(o + 54272))[r] = hi;
            ((unsigned short*)(o + 58368))[r] = lo;
        }
        return;
    }
    // ---- LayerNorm + qkv part (64 pixels per block) ----
    __shared__ float Xs[64][64];
    __shared__ float Ws[64][80];
    __shared__ float r1[4][64], r2[4][64];
    int lb = bid - 244;
    int pl = tid & 63, cq = tid >> 6;
    int b = lb >> 6;
    int pix0 = (lb & 63) * 64;
    int pix = pix0 + pl;
    for (int i = tid; i < 5120; i += 256) {
        int ci = i / 80, j = i - ci * 80;
        float v = j < 8 ? qw[j * 64 + ci] : (j < 16 ? kw[(j - 8) * 64 + ci] : vw[(j - 16) * 64 + ci]);
        ((float*)Ws)[i] = v;
    }
    const float* p = x + (size_t)b * NC * NHW + pix;
    float v[16]; float s = 0.f, ss = 0.f;
    #pragma unroll
    for (int k = 0; k < 16; ++k) {
        float f = p[(size_t)(cq * 16 + k) * NHW];
        v[k] = f; s += f; ss += f * f;
    }
    r1[cq][pl] = s; r2[cq][pl] = ss;
    __syncthreads();
    float S  = r1[0][pl] + r1[1][pl] + r1[2][pl] + r1[3][pl];
    float SS = r2[0][pl] + r2[1][pl] + r2[2][pl] + r2[3][pl];
    float mean = S * (1.0f / 64);
    float rstd = rsqrtf(SS * (1.0f / 64) - mean * mean + 1e-5f);
    ushort8 t0, t1;
    #pragma unroll
    for (int k = 0; k < 16; ++k) {
        int c = cq * 16 + k;
        float nv = (v[k] - mean) * rstd * lnw[c] + lnb[c];
        Xs[c][pl] = nv;
        unsigned short bv = f2bf(nv);
        if (k < 8) t0[k] = bv; else t1[k - 8] = bv;
    }
    unsigned short* tp = xnT + ((size_t)b * NHW + pix) * 64 + cq * 16;
    *(ushort8*)tp = t0;
    *(ushort8*)(tp + 8) = t1;
    __syncthreads();
    int co0 = cq * 20;
    float acc[20];
    #pragma unroll
    for (int j = 0; j < 20; ++j) acc[j] = 0.f;
    for (int ci = 0; ci < 64; ++ci) {
        float xv = Xs[ci][pl];
        const float* wr = &Ws[ci][co0];
        #pragma unroll
        for (int j = 0; j < 20; ++j) acc[j] = fmaf(xv, wr[j], acc[j]);
    }
    #pragma unroll
    for (int j = 0; j < 20; ++j) {
        int co = co0 + j;
        float bsv; unsigned short* dst;
        if (co < 8)       { bsv = qb[co];      dst = q1 + ((size_t)b * NC8 + co) * NHW + pix; }
        else if (co < 16) { bsv = kb[co - 8];  dst = k1 + ((size_t)b * NC8 + co - 8) * NHW + pix; }
        else              { bsv = vb[co - 16]; dst = v1 + ((size_t)b * NC + co - 16) * NHW + pix; }
        *dst = f2bf(acc[j] + bsv);
    }
}

// ---------------- merged: VECTORIZED depthwise 3x3 (bid<320) + CAB conv1 MFMA (bid>=320) ----
__global__ __launch_bounds__(512) void k_dwcab1(
        const unsigned short* __restrict__ q1, const unsigned short* __restrict__ k1,
        const unsigned short* __restrict__ v1,
        const float* __restrict__ qkw, const float* __restrict__ qkb,
        const float* __restrict__ vw, const float* __restrict__ vb,
        unsigned short* __restrict__ qdb, unsigned short* __restrict__ kdb,
        unsigned short* __restrict__ v8,
        const unsigned short* __restrict__ xnT,
        const unsigned short* __restrict__ Ah, const unsigned short* __restrict__ Al,
        const float* __restrict__ bias, unsigned short* __restrict__ y1T) {
    __shared__ float Rs[2048];
    int bid = blockIdx.x;
    int tid = threadIdx.x;
    if (bid < 320) {
        int yv = bid % 80, b = bid / 80;
        int y = tid >> 3, x0 = (tid & 7) * 8;
        const unsigned short* ip;
        const float* wp;
        float bs;
        if (yv < 16) {
            int c = yv & 7;
            ip = (yv < 8 ? q1 : k1) + ((size_t)b * NC8 + c) * NHW;
            wp = qkw + c * 9; bs = qkb[c];
        } else {
            int c = yv - 16;
            ip = v1 + ((size_t)b * NC + c) * NHW;
            wp = vw + c * 9; bs = vb[c];
        }
        float w9[9];
        #pragma unroll
        for (int t = 0; t < 9; ++t) w9[t] = wp[t];
        float acc[8];
        #pragma unroll
        for (int j = 0; j < 8; ++j) acc[j] = bs;
        #pragma unroll
        for (int dy = -1; dy <= 1; ++dy) {
            int yy = y + dy;
            if ((unsigned)yy >= 64u) continue;
            const unsigned short* rp = ip + yy * 64;
            float cv[10];
            cv[0] = (x0 > 0) ? bf2f(rp[x0 - 1]) : 0.f;
            ushort8 ctr = *(const ushort8*)(rp + x0);
            #pragma unroll
            for (int j = 0; j < 8; ++j) cv[j + 1] = bf2f(ctr[j]);
            cv[9] = (x0 + 8 < 64) ? bf2f(rp[x0 + 8]) : 0.f;
            const float* wr = &w9[(dy + 1) * 3];
            #pragma unroll
            for (int j = 0; j < 8; ++j)
                acc[j] = fmaf(wr[0], cv[j], fmaf(wr[1], cv[j + 1], fmaf(wr[2], cv[j + 2], acc[j])));
        }
        int px0 = tid * 8;
        if (yv < 16) {
            int c = yv & 7;
            unsigned short* outp = (yv < 8 ? qdb : kdb) + ((size_t)b * NHW + px0) * NC8 + c;
            #pragma unroll
            for (int j = 0; j < 8; ++j) outp[j * NC8] = f2bf(acc[j]);
        } else {
            int c = yv - 16;
            ushort8 pk;
            #pragma unroll
            for (int j = 0; j < 8; ++j) pk[j] = f2bf(acc[j]);
            *(ushort8*)(v8 + (((size_t)b * 512 + (px0 >> 3)) * NC + c) * 8) = pk;
        }
        return;
    }
    int r = bid - 320;
    int y = r & 63, b = r >> 6;
    int w = tid >> 6, lane = tid & 63;
    int il = lane & 15, g = lane >> 4;
    int frag = w & 3, kh = w >> 2;
    int xloc = frag * 16 + il;
    f32x4 acc[2];
    acc[0] = (f32x4){0.f, 0.f, 0.f, 0.f};
    acc[1] = (f32x4){0.f, 0.f, 0.f, 0.f};
    #pragma unroll
    for (int si = 0; si < 9; ++si) {
        int s = kh * 9 + si;
        int tap = s >> 1;
        int ci0 = (s & 1) * 32;
        int dyv = tap / 3 - 1, dxv = tap - (tap / 3) * 3 - 1;
        int xx = xloc + dxv, yy = y + dyv;
        bf16x8 bv = (bf16x8)(short)0;
        if (((unsigned)xx < 64u) && ((unsigned)yy < 64u))
            bv = *(const bf16x8*)(xnT + ((size_t)b * NHW + yy * 64 + xx) * 64 + ci0 + g * 8);
        #pragma unroll
        for (int f = 0; f < 2; ++f) {
            bf16x8 ahv = *(const bf16x8*)(Ah + ((size_t)(f * 18 + s) * 64 + lane) * 8);
            bf16x8 alv = *(const bf16x8*)(Al + ((size_t)(f * 18 + s) * 64 + lane) * 8);
            acc[f] = __builtin_amdgcn_mfma_f32_16x16x32_bf16(ahv, bv, acc[f], 0, 0, 0);
            acc[f] = __builtin_amdgcn_mfma_f32_16x16x32_bf16(alv, bv, acc[f], 0, 0, 0);
        }
    }
    if (kh == 1) {
        #pragma unroll
        for (int f = 0; f < 2; ++f)
            #pragma unroll
            for (int e = 0; e < 4; ++e)
                Rs[((frag * 2 + f) * 4 + e) * 64 + lane] = acc[f][e];
    }
    __syncthreads();
    if (kh == 0) {
        #pragma unroll
        for (int f = 0; f < 2; ++f) {
            ushort4 pk;
            #pragma unroll
            for (int e = 0; e < 4; ++e) {
                float v = acc[f][e] + Rs[((frag * 2 + f) * 4 + e) * 64 + lane];
                int co = f * 16 + g * 4 + e;
                float rr = 0.f;
                if (co < 21) rr = gelu_exact(v + bias[co]);
                ((unsigned short*)&pk)[e] = f2bf(rr);
            }
            *(ushort4*)(y1T + ((size_t)b * NHW + y * 64 + xloc) * 32 + f * 16 + g * 4) = pk;
        }
    }
}

// ---------------- merged: flash attention (bid<512) + CAB conv2 MFMA (bid>=512) ----------------
__global__ __launch_bounds__(512) void k_flashcab2(
        const unsigned short* __restrict__ qdb, const unsigned short* __restrict__ kdb,
        const unsigned short* __restrict__ v8, unsigned short* __restrict__ O,
        const unsigned short* __restrict__ y1T,
        const unsigned short* __restrict__ Ah, const unsigned short* __restrict__ Al,
        const float* __restrict__ bias, unsigned short* __restrict__ ycT,
        float* __restrict__ pool) {
    __shared__ __align__(16) char smem[35840];
    int bid = blockIdx.x;
    int tid = threadIdx.x;
    int w = tid >> 6, lane = tid & 63;
    int g = lane >> 4, il = lane & 15;
    if (bid < 512) {
        int i0 = (bid & 127) * 32, b = bid >> 7;
        unsigned short (*P)[72] = (unsigned short (*)[72])(smem + w * 2304);
        bf16x8 qb0 = (bf16x8)(short)0, qb1 = (bf16x8)(short)0;
        if (g == 0) {
            qb0 = *(const bf16x8*)(qdb + (size_t)(b * NHW + i0 + il) * NC8);
            qb1 = *(const bf16x8*)(qdb + (size_t)(b * NHW + i0 + 16 + il) * NC8);
        }
        f32x4 acc0[4], acc1[4];
        #pragma unroll
        for (int ct = 0; ct < 4; ++ct) {
            acc0[ct] = (f32x4){0.f, 0.f, 0.f, 0.f};
            acc1[ct] = (f32x4){0.f, 0.f, 0.f, 0.f};
        }
        float La0 = 0.f, La1 = 0.f;
        bf16x8 kn[4];
        #pragma unroll
        for (int t = 0; t < 4; ++t) {
            kn[t] = (bf16x8)(short)0;
            if (g == 0) kn[t] = *(const bf16x8*)(kdb + (size_t)(b * NHW + w * 512 + 16 * t + il) * NC8);
        }
        for (int jt = 0; jt < 8; ++jt) {
            int j0 = w * 512 + jt * 64;
            int ch0 = b * 512 + (j0 >> 3);
            bf16x8 va[2][4];
            #pragma unroll
            for (int kc = 0; kc < 2; ++kc)
                #pragma unroll
                for (int ct = 0; ct < 4; ++ct)
                    va[kc][ct] = *(const bf16x8*)(v8 +
                        ((size_t)(ch0 + kc * 4 + g) * NC + ct * 16 + il) * 8);
            bf16x8 ka[4];
            #pragma unroll
            for (int t = 0; t < 4; ++t) ka[t] = kn[t];
            if (jt < 7) {
                #pragma unroll
                for (int t = 0; t < 4; ++t) {
                    kn[t] = (bf16x8)(short)0;
                    if (g == 0) kn[t] = *(const bf16x8*)(kdb + (size_t)(b * NHW + j0 + 64 + 16 * t + il) * NC8);
                }
            }
            #pragma unroll
            for (int t = 0; t < 4; ++t) {
                f32x4 sv = __builtin_amdgcn_mfma_f32_16x16x32_bf16(ka[t], qb0, (f32x4){0.f, 0.f, 0.f, 0.f}, 0, 0, 0);
                float p0 = __expf(sv[0]), p1 = __expf(sv[1]);
                float p2 = __expf(sv[2]), p3 = __expf(sv[3]);
                La0 += (p0 + p1) + (p2 + p3);
                ushort4 pk;
                pk.x = f2bf(p0); pk.y = f2bf(p1); pk.z = f2bf(p2); pk.w = f2bf(p3);
                *(ushort4*)&P[il][16 * t + 4 * g] = pk;
            }
            #pragma unroll
            for (int kc = 0; kc < 2; ++kc) {
                bf16x8 pb = *(const bf16x8*)&P[il][kc * 32 + 8 * g];
                #pragma unroll
                for (int ct = 0; ct < 4; ++ct)
                    acc0[ct] = __builtin_amdgcn_mfma_f32_16x16x32_bf16(va[kc][ct], pb, acc0[ct], 0, 0, 0);
            }
            #pragma unroll
            for (int t = 0; t < 4; ++t) {
                f32x4 sv = __builtin_amdgcn_mfma_f32_16x16x32_bf16(ka[t], qb1, (f32x4){0.f, 0.f, 0.f, 0.f}, 0, 0, 0);
                float p0 = __expf(sv[0]), p1 = __expf(sv[1]);
                float p2 = __expf(sv[2]), p3 = __expf(sv[3]);
                La1 += (p0 + p1) + (p2 + p3);
                ushort4 pk;
                pk.x = f2bf(p0); pk.y = f2bf(p1); pk.z = f2bf(p2); pk.w = f2bf(p3);
                *(ushort4*)&P[il][16 * t + 4 * g] = pk;
            }
            #pragma unroll
            for (int kc = 0; kc < 2; ++kc) {
                bf16x8 pb = *(const bf16x8*)&P[il][kc * 32 + 8 * g];
                #pragma unroll
                for (int ct = 0; ct < 4; ++ct)
                    acc1[ct] = __builtin_amdgcn_mfma_f32_16x16x32_bf16(va[kc][ct], pb, acc1[ct], 0, 0, 0);
            }
        }
        La0 += __shfl_xor(La0, 16, 64); La0 += __shfl_xor(La0, 32, 64);
        La1 += __shfl_xor(La1, 16, 64); La1 += __shfl_xor(La1, 32, 64);

        __syncthreads();
        unsigned short* Ocm = (unsigned short*)smem;
        float* Lw = (float*)(smem + 34816);
        #pragma unroll
        for (int ct = 0; ct < 4; ++ct)
            #pragma unroll
            for (int e = 0; e < 4; ++e) {
                int c = ct * 16 + 4 * g + e;
                Ocm[(w * 2 + 0) * 1088 + c * 17 + il] = f2bf(acc0[ct][e]);
                Ocm[(w * 2 + 1) * 1088 + c * 17 + il] = f2bf(acc1[ct][e]);
            }
        if (lane < 16) {
            Lw[(w * 2 + 0) * 16 + il] = La0;
            Lw[(w * 2 + 1) * 16 + il] = La1;
        }
        __syncthreads();

        int st = tid >> 8, rem = tid & 255;
        int ic = rem & 15, ch = rem >> 4;
        float l = 0.f;
        #pragma unroll
        for (int w2 = 0; w2 < 8; ++w2) l += Lw[(w2 * 2 + st) * 16 + ic];
        float rl = 1.0f / l;
        #pragma unroll
        for (int cc = 0; cc < 4; ++cc) {
            int c = cc * 16 + ch;
            float o = 0.f;
            #pragma unroll
            for (int w2 = 0; w2 < 8; ++w2) o += bf2f(Ocm[(w2 * 2 + st) * 1088 + c * 17 + ic]);
            O[(size_t)(b * NC + c) * NHW + i0 + st * 16 + ic] = f2bf(o * rl);
        }
        return;
    }
    float* Rs = (float*)smem;
    float (*Ssum)[64] = (float (*)[64])(smem + 16384);
    int r = bid - 512;
    int y = r & 63, b = r >> 6;
    int frag = w & 3, kh = w >> 2;
    int xloc = frag * 16 + il;
    f32x4 acc[4];
    #pragma unroll
    for (int f = 0; f < 4; ++f) acc[f] = (f32x4){0.f, 0.f, 0.f, 0.f};
    #pragma unroll
    for (int si = 0; si < 5; ++si) {
        if (!(kh == 1 && si == 4)) {
            int s = kh * 5 + si;
            int dyv = s / 3 - 1, dxv = s - (s / 3) * 3 - 1;
            int xx = xloc + dxv, yy = y + dyv;
            bf16x8 bv = (bf16x8)(short)0;
            if (((unsigned)xx < 64u) && ((unsigned)yy < 64u))
                bv = *(const bf16x8*)(y1T + ((size_t)b * NHW + yy * 64 + xx) * 32 + g * 8);
            #pragma unroll
            for (int f = 0; f < 4; ++f) {
                bf16x8 ahv = *(const bf16x8*)(Ah + ((size_t)(f * 9 + s) * 64 + lane) * 8);
                bf16x8 alv = *(const bf16x8*)(Al + ((size_t)(f * 9 + s) * 64 + lane) * 8);
                acc[f] = __builtin_amdgcn_mfma_f32_16x16x32_bf16(ahv, bv, acc[f], 0, 0, 0);
                acc[f] = __builtin_amdgcn_mfma_f32_16x16x32_bf16(alv, bv, acc[f], 0, 0, 0);
            }
        }
    }
    if (kh == 1) {
        #pragma unroll
        for (int f = 0; f < 4; ++f)
            #pragma unroll
            for (int e = 0; e < 4; ++e)
                Rs[((frag * 4 + f) * 4 + e) * 64 + lane] = acc[f][e];
    }
    __syncthreads();
    if (kh == 0) {
        #pragma unroll
        for (int f = 0; f < 4; ++f) {
            ushort4 pk;
            #pragma unroll
            for (int e = 0; e < 4; ++e) {
                int co = f * 16 + g * 4 + e;
                float v = acc[f][e] + Rs[((frag * 4 + f) * 4 + e) * 64 + lane] + bias[co];
                ((unsigned short*)&pk)[e] = f2bf(v);
                float ps = v;
                ps += __shfl_xor(ps, 1, 64);
                ps += __shfl_xor(ps, 2, 64);
                ps += __shfl_xor(ps, 4, 64);
                ps += __shfl_xor(ps, 8, 64);
                if (il == 0) Ssum[frag][co] = ps;
            }
            *(ushort4*)(ycT + ((size_t)b * NHW + y * 64 + xloc) * 64 + f * 16 + g * 4) = pk;
        }
    }
    __syncthreads();
    if (tid < 64) {
        float t = Ssum[0][tid] + Ssum[1][tid] + Ssum[2][tid] + Ssum[3][tid];
        atomicAdd(&pool[b * NC + tid], t);
    }
}

// ---------------- proj + CA + residuals + fused LN2; 32-px tiles (512 blocks) ----------------
__global__ __launch_bounds__(512) void k_fsum2(const unsigned short* __restrict__ O,
        const float* __restrict__ pwt, const float* __restrict__ pb,
        const float* __restrict__ gamma, const unsigned short* __restrict__ xnT,
        const unsigned short* __restrict__ ycT, const float* __restrict__ pool,
        const float* __restrict__ cw1, const float* __restrict__ cb1,
        const float* __restrict__ cw2, const float* __restrict__ cb2,
        const float* __restrict__ x, const float* __restrict__ lnw,
        const float* __restrict__ lnb, unsigned short* __restrict__ fsum,
        unsigned short* __restrict__ fs1T) {
    __shared__ unsigned short Os[64][32];
    __shared__ float Ws[64][64];
    __shared__ float Fs[64][34];
    __shared__ float mean_s[32], rstd_s[32];
    int tid = threadIdx.x;
    int pix0 = blockIdx.x * 32, b = blockIdx.y;
    {
        int c = tid >> 3, q4 = tid & 7;
        *(ushort4*)&Os[c][q4 * 4] = *(const ushort4*)(O + ((size_t)b * NC + c) * NHW + pix0 + q4 * 4);
    }
    for (int i = tid; i < 1024; i += 512)
        *(float4*)&((float*)Ws)[i * 4] = *(const float4*)&pwt[i * 4];
    __syncthreads();
    float h0 = cb1[0], h1 = cb1[1];
    for (int ci = 0; ci < NC; ++ci) {
        float pv = pool[b * NC + ci] * (1.0f / NHW);
        h0 += cw1[ci] * pv;
        h1 += cw1[NC + ci] * pv;
    }
    h0 = fmaxf(h0, 0.f); h1 = fmaxf(h1, 0.f);
    int p2 = (tid & 15) * 2, g = tid >> 4;   // 32 groups x 2 co
    int co0 = g * 2;
    float scv[2];
    #pragma unroll
    for (int j = 0; j < 2; ++j) {
        int c = co0 + j;
        float z = cw2[c * 2] * h0 + cw2[c * 2 + 1] * h1 + cb2[c];
        scv[j] = 1.0f / (1.0f + __expf(-z));
    }
    float a0[2], a1[2];
    a0[0] = 0.f; a0[1] = 0.f; a1[0] = 0.f; a1[1] = 0.f;
    for (int ci = 0; ci < 64; ++ci) {
        ushort2 uv = *(const ushort2*)&Os[ci][p2];
        float ox = bf2f(uv.x), oy = bf2f(uv.y);
        float2 wv = *(const float2*)&Ws[ci][co0];
        a0[0] = fmaf(ox, wv.x, a0[0]);
        a0[1] = fmaf(ox, wv.y, a0[1]);
        a1[0] = fmaf(oy, wv.x, a1[0]);
        a1[1] = fmaf(oy, wv.y, a1[1]);
    }
    float gg = gamma[0];
    size_t base = (size_t)b * NC * NHW + pix0 + p2;
    const unsigned short* xtp = xnT + ((size_t)b * NHW + pix0 + p2) * 64 + co0;
    const unsigned short* ytp = ycT + ((size_t)b * NHW + pix0 + p2) * 64 + co0;
    ushort2 xa = *(const ushort2*)xtp, xb = *(const ushort2*)(xtp + 64);
    ushort2 ya = *(const ushort2*)ytp, yb = *(const ushort2*)(ytp + 64);
    float f0[2], f1[2];
    #pragma unroll
    for (int j = 0; j < 2; ++j) {
        int c = co0 + j;
        size_t n = base + (size_t)c * NHW;
        float pbv = pb[c];
        float2 xv = *(const float2*)&x[n];
        f0[j] = gg * (a0[j] + pbv) + bf2f(((const unsigned short*)&xa)[j])
              + bf2f(((const unsigned short*)&ya)[j]) * scv[j] + xv.x;
        f1[j] = gg * (a1[j] + pbv) + bf2f(((const unsigned short*)&xb)[j])
              + bf2f(((const unsigned short*)&yb)[j]) * scv[j] + xv.y;
        ushort2 o = { f2bf(f0[j]), f2bf(f1[j]) };
        *(ushort2*)&fsum[n] = o;
        Fs[c][p2] = f0[j]; Fs[c][p2 + 1] = f1[j];
    }
    __syncthreads();
    if (tid < 32) {
        float s = 0.f, ss = 0.f;
        for (int c = 0; c < 64; ++c) { float v = Fs[c][tid]; s += v; ss += v * v; }
        float mean = s * (1.0f / 64);
        mean_s[tid] = mean;
        rstd_s[tid] = rsqrtf(ss * (1.0f / 64) - mean * mean + 1e-5f);
    }
    __syncthreads();
    float m0 = mean_s[p2], r0 = rstd_s[p2];
    float m1 = mean_s[p2 + 1], r1 = rstd_s[p2 + 1];
    ushort2 oA, oB;
    #pragma unroll
    for (int j = 0; j < 2; ++j) {
        int c = co0 + j;
        float lw = lnw[c], lb = lnb[c];
        ((unsigned short*)&oA)[j] = f2bf((f0[j] - m0) * r0 * lw + lb);
        ((unsigned short*)&oB)[j] = f2bf((f1[j] - m1) * r1 * lw + lb);
    }
    unsigned short* fp = fs1T + ((size_t)b * NHW + pix0 + p2) * 64 + co0;
    *(ushort2*)fp = oA;
    *(ushort2*)(fp + 64) = oB;
}

// ---------------- fused MLP as MFMA implicit GEMM; 32-px tiles (512 blocks) ----------------
__global__ __launch_bounds__(512) void k_mlp(const unsigned short* __restrict__ fs1T,
        const unsigned short* __restrict__ A1h, const unsigned short* __restrict__ A1l,
        const float* __restrict__ b1,
        const unsigned short* __restrict__ A2h, const unsigned short* __restrict__ A2l,
        const float* __restrict__ b2,
        const unsigned short* __restrict__ fs, float* __restrict__ out) {
    __shared__ unsigned short Hs[32][136];
    int tid = threadIdx.x;
    int w = tid >> 6, lane = tid & 63;
    int il = lane & 15, g = lane >> 4;
    int frag = w & 1, sub = w >> 1;
    int pix0 = blockIdx.x * 32, b = blockIdx.y;
    int xloc = frag * 16 + il;
    const unsigned short* bp = fs1T + ((size_t)b * NHW + pix0 + xloc) * 64;
    // ---- fc1 ----
    f32x4 acc[2];
    acc[0] = (f32x4){0.f, 0.f, 0.f, 0.f};
    acc[1] = (f32x4){0.f, 0.f, 0.f, 0.f};
    #pragma unroll
    for (int s = 0; s < 2; ++s) {
        bf16x8 bv = *(const bf16x8*)(bp + s * 32 + g * 8);
        #pragma unroll
        for (int fi = 0; fi < 2; ++fi) {
            int F = sub * 2 + fi;
            bf16x8 ah = *(const bf16x8*)(A1h + ((size_t)(F * 2 + s) * 64 + lane) * 8);
            bf16x8 al = *(const bf16x8*)(A1l + ((size_t)(F * 2 + s) * 64 + lane) * 8);
            acc[fi] = __builtin_amdgcn_mfma_f32_16x16x32_bf16(ah, bv, acc[fi], 0, 0, 0);
            acc[fi] = __builtin_amdgcn_mfma_f32_16x16x32_bf16(al, bv, acc[fi], 0, 0, 0);
        }
    }
    #pragma unroll
    for (int fi = 0; fi < 2; ++fi) {
        int F = sub * 2 + fi;
        ushort4 pk;
        #pragma unroll
        for (int e = 0; e < 4; ++e) {
            int m = F * 16 + g * 4 + e;
            ((unsigned short*)&pk)[e] = f2bf(gelu_exact(acc[fi][e] + b1[m]));
        }
        *(ushort4*)&Hs[xloc][F * 16 + g * 4] = pk;
    }
    __syncthreads();
    // ---- fc2 ----
    f32x4 acc2 = (f32x4){0.f, 0.f, 0.f, 0.f};
    #pragma unroll
    for (int s = 0; s < 4; ++s) {
        bf16x8 bv = *(const bf16x8*)&Hs[xloc][s * 32 + g * 8];
        int F2 = sub;
        bf16x8 ah = *(const bf16x8*)(A2h + ((size_t)(F2 * 4 + s) * 64 + lane) * 8);
        bf16x8 al = *(const bf16x8*)(A2l + ((size_t)(F2 * 4 + s) * 64 + lane) * 8);
        acc2 = __builtin_amdgcn_mfma_f32_16x16x32_bf16(ah, bv, acc2, 0, 0, 0);
        acc2 = __builtin_amdgcn_mfma_f32_16x16x32_bf16(al, bv, acc2, 0, 0, 0);
    }
    {
        int c0 = sub * 16 + g * 4;
        size_t ob = ((size_t)b * NHW + pix0 + xloc) * 64 + c0;
        ushort4 rv = *(const ushort4*)&fs[ob];
        float4 o4;
        o4.x = acc2[0] + b2[c0 + 0] + bf2f(rv.x);
        o4.y = acc2[1] + b2[c0 + 1] + bf2f(rv.y);
        o4.z = acc2[2] + b2[c0 + 2] + bf2f(rv.z);
        o4.w = acc2[3] + b2[c0 + 3] + bf2f(rv.w);
        *(float4*)&out[ob] = o4;
    }
}

extern "C" void kernel_launch(void* const* d_in, const int* in_sizes, int n_in,
                              void* d_out, int out_size, void* d_ws, size_t ws_size,
                              hipStream_t stream) {
    const float* x        = (const float*)d_in[0];
    const float* ln_w     = (const float*)d_in[1];
    const float* ln_b     = (const float*)d_in[2];
    const float* q_w      = (const float*)d_in[3];
    const float* q_b      = (const float*)d_in[4];
    const float* k_w      = (const float*)d_in[5];
    const float* k_b      = (const float*)d_in[6];
    const float* v_w      = (const float*)d_in[7];
    const float* v_b      = (const float*)d_in[8];
    const float* qkdw_w   = (const float*)d_in[9];
    const float* qkdw_b   = (const float*)d_in[10];
    const float* vdw_w    = (const float*)d_in[11];
    const float* vdw_b    = (const float*)d_in[12];
    const float* proj_w   = (const float*)d_in[13];
    const float* proj_b   = (const float*)d_in[14];
    const float* gamma    = (const float*)d_in[15];
    const float* cab_w1   = (const float*)d_in[16];
    const float* cab_b1   = (const float*)d_in[17];
    const float* cab_w2   = (const float*)d_in[18];
    const float* cab_b2   = (const float*)d_in[19];
    const float* ca_w1    = (const float*)d_in[20];
    const float* ca_b1    = (const float*)d_in[21];
    const float* ca_w2    = (const float*)d_in[22];
    const float* ca_b2    = (const float*)d_in[23];
    const float* fc1_w    = (const float*)d_in[24];
    const float* fc1_b    = (const float*)d_in[25];
    const float* fc2_w    = (const float*)d_in[26];
    const float* fc2_b    = (const float*)d_in[27];
    float* out = (float*)d_out;

    char* ws = (char*)d_ws;
    size_t off = 0;
    auto alloc = [&](size_t bytes) { void* p = ws + off; off += (bytes + 255) & ~(size_t)255; return p; };
    unsigned short* xnT = (unsigned short*)alloc((size_t)NB * NHW * NC * 2);
    unsigned short* q1  = (unsigned short*)alloc((size_t)NB * NC8 * NHW * 2);
    unsigned short* k1  = (unsigned short*)alloc((size_t)NB * NC8 * NHW * 2);
    unsigned short* v1  = (unsigned short*)alloc((size_t)NB * NC * NHW * 2);
    unsigned short* qdb = (unsigned short*)alloc((size_t)NB * NHW * NC8 * 2);
    unsigned short* kdb = (unsigned short*)alloc((size_t)NB * NHW * NC8 * 2);
    unsigned short* vdb = (unsigned short*)alloc((size_t)NB * NC * NHW * 2);
    unsigned short* O   = (unsigned short*)alloc((size_t)NB * NC * NHW * 2);
    unsigned short* y1T = (unsigned short*)alloc((size_t)NB * NHW * 32 * 2);
    unsigned short* ycT = (unsigned short*)alloc((size_t)NB * NHW * NC * 2);
    float* pool  = (float*)alloc(256 * 4);
    unsigned short* fsum = (unsigned short*)alloc((size_t)NB * NC * NHW * 2);
    unsigned short* fs1T = (unsigned short*)alloc((size_t)NB * NHW * NC * 2);
    float* wpack = (float*)alloc(62464 * 4);

    float* proj_wt = wpack + 5120;
    unsigned short* cab1Ah = (unsigned short*)(wpack + 9216);
    unsigned short* cab1Al = (unsigned short*)(wpack + 18432);
    unsigned short* cab2Ah = (unsigned short*)(wpack + 27648);
    unsigned short* cab2Al = (unsigned short*)(wpack + 36864);
    unsigned short* fc1h   = (unsigned short*)(wpack + 46080);
    unsigned short* fc1l   = (unsigned short*)(wpack + 50176);
    unsigned short* fc2h   = (unsigned short*)(wpack + 54272);
    unsigned short* fc2l   = (unsigned short*)(wpack + 58368);

    dim3 blk(256);
    dim3 blk5(512);

    k_prep<<<dim3(500), blk, 0, stream>>>(q_w, k_w, v_w, cab_w1, cab_w2, proj_w, fc1_w, fc2_w,
                                          wpack, pool, x, ln_w, ln_b, q_b, k_b, v_b,
                                          xnT, q1, k1, v1);
    k_dwcab1<<<dim3(576), blk5, 0, stream>>>(q1, k1, v1, qkdw_w, qkdw_b, vdw_w, vdw_b,
                                             qdb, kdb, vdb, xnT, cab1Ah, cab1Al, cab_b1, y1T);
    k_flashcab2<<<dim3(768), blk5, 0, stream>>>(qdb, kdb, vdb, O, y1T, cab2Ah, cab2Al,
                                                cab_b2, ycT, pool);
    k_fsum2<<<dim3(128, NB), blk5, 0, stream>>>(O, proj_wt, proj_b, gamma, xnT, ycT, pool,
                                                ca_w1, ca_b1, ca_w2, ca_b2, x, ln_w, ln_b,
                                                fsum, fs1T);
    k_mlp<<<dim3(128, NB), blk5, 0, stream>>>(fs1T, fc1h, fc1l, fc1_b, fc2h, fc2l, fc2_b,
                                              fsum, out);
}